// Round 1
// baseline (645.393 us; speedup 1.0000x reference)
//
#include <hip/hip_runtime.h>
#include <math.h>

#define NNODES 50000
#define NEDGES 800000
#define ETOT   (NEDGES + NNODES)   // edges + self loops
#define F      64

// ---------------------------------------------------------------------------
// Kernel A: h = x @ W ; alpha_s = h . a_src ; alpha_d = h . a_dst
// One wave (64 lanes) per node; block = 256 threads = 4 nodes.
// ---------------------------------------------------------------------------
__global__ __launch_bounds__(256) void node_linear(
    const float* __restrict__ x, const float* __restrict__ W,
    const float* __restrict__ a_src, const float* __restrict__ a_dst,
    float* __restrict__ h, float* __restrict__ as_, float* __restrict__ ad_)
{
    __shared__ float Ws[F * F];
    __shared__ float asv[F], adv[F];
    __shared__ float xrow[4][F];

    const int tid  = threadIdx.x;
    const int wave = tid >> 6;
    const int lane = tid & 63;
    const int node = blockIdx.x * 4 + wave;   // grid sized so node < NNODES always

    for (int i = tid; i < F * F; i += 256) Ws[i] = W[i];
    if (tid < F) { asv[tid] = a_src[tid]; adv[tid] = a_dst[tid]; }
    xrow[wave][lane] = x[node * F + lane];
    __syncthreads();

    float acc = 0.f;
#pragma unroll
    for (int k = 0; k < F; ++k)
        acc = fmaf(xrow[wave][k], Ws[k * F + lane], acc);

    h[node * F + lane] = acc;

    float vs = acc * asv[lane];
    float vd = acc * adv[lane];
#pragma unroll
    for (int off = 32; off > 0; off >>= 1) {
        vs += __shfl_down(vs, off, 64);
        vd += __shfl_down(vd, off, 64);
    }
    if (lane == 0) { as_[node] = vs; ad_[node] = vd; }
}

// ---------------------------------------------------------------------------
// Kernel B: per edge e: ex = exp(leakyrelu(as[src]+ad[dst], 0.2)); z[dst]+=ex
// (softmax max-shift skipped: shift-invariant, values small enough for f32)
// ---------------------------------------------------------------------------
__global__ __launch_bounds__(256) void edge_softmax_den(
    const int* __restrict__ src, const int* __restrict__ dst,
    const float* __restrict__ as_, const float* __restrict__ ad_,
    float* __restrict__ ex, float* __restrict__ z)
{
    const int e = blockIdx.x * 256 + threadIdx.x;
    if (e >= ETOT) return;
    int s, d;
    if (e < NEDGES) { s = src[e]; d = dst[e]; }
    else            { s = e - NEDGES; d = s; }   // self loop
    float t = as_[s] + ad_[d];
    t = (t > 0.f) ? t : 0.2f * t;
    float ev = __expf(t);
    ex[e] = ev;
    atomicAdd(&z[d], ev);
}

// ---------------------------------------------------------------------------
// Kernel C: per edge e: acc[dst] += h[src] * (ex[e] / (z[dst]+1e-16))
// One wave per edge; lane = feature.
// ---------------------------------------------------------------------------
__global__ __launch_bounds__(256) void edge_aggregate(
    const int* __restrict__ src, const int* __restrict__ dst,
    const float* __restrict__ h, const float* __restrict__ ex,
    const float* __restrict__ z, float* __restrict__ acc)
{
    const int gid  = blockIdx.x * 256 + threadIdx.x;
    const int e    = gid >> 6;
    const int lane = gid & 63;
    if (e >= ETOT) return;
    int s, d;
    if (e < NEDGES) { s = src[e]; d = dst[e]; }
    else            { s = e - NEDGES; d = s; }
    const float alpha = ex[e] / (z[d] + 1e-16f);
    const float v = h[s * F + lane] * alpha;
    atomicAdd(&acc[d * F + lane], v);
}

// ---------------------------------------------------------------------------
// Kernel D: in-place acc = leaky_relu(acc + b, 0.01)   (between layers)
// ---------------------------------------------------------------------------
__global__ __launch_bounds__(256) void bias_act(
    float* __restrict__ acc, const float* __restrict__ b)
{
    const int i = blockIdx.x * 256 + threadIdx.x;   // exactly NNODES*F threads
    float v = acc[i] + b[i & 63];
    acc[i] = (v > 0.f) ? v : 0.01f * v;
}

// ---------------------------------------------------------------------------
// Kernel E: out = leaky_relu(acc + b, 0.01) + x   (final, with residual)
// ---------------------------------------------------------------------------
__global__ __launch_bounds__(256) void bias_act_res(
    const float* __restrict__ acc, const float* __restrict__ b,
    const float* __restrict__ x, float* __restrict__ out)
{
    const int i = blockIdx.x * 256 + threadIdx.x;
    float v = acc[i] + b[i & 63];
    v = (v > 0.f) ? v : 0.01f * v;
    out[i] = v + x[i];
}

extern "C" void kernel_launch(void* const* d_in, const int* in_sizes, int n_in,
                              void* d_out, int out_size, void* d_ws, size_t ws_size,
                              hipStream_t stream)
{
    const float* x   = (const float*)d_in[0];
    const int*   ei  = (const int*)  d_in[1];   // [2, NEDGES] row-major
    const float* W0  = (const float*)d_in[2];
    const float* as0 = (const float*)d_in[3];
    const float* ad0 = (const float*)d_in[4];
    const float* b0  = (const float*)d_in[5];
    const float* W1  = (const float*)d_in[6];
    const float* as1 = (const float*)d_in[7];
    const float* ad1 = (const float*)d_in[8];
    const float* b1  = (const float*)d_in[9];
    float* out = (float*)d_out;

    const int* src = ei;
    const int* dst = ei + NEDGES;

    // workspace carve-up
    char* ws = (char*)d_ws;
    float* h    = (float*)ws; ws += (size_t)NNODES * F * 4;
    float* acc  = (float*)ws; ws += (size_t)NNODES * F * 4;
    float* as_  = (float*)ws; ws += (size_t)NNODES * 4;
    float* ad_  = (float*)ws; ws += (size_t)NNODES * 4;
    float* z    = (float*)ws; ws += (size_t)NNODES * 4;
    float* ex   = (float*)ws; ws += (size_t)ETOT * 4;

    const int nodeBlocks = NNODES / 4;                 // 12500 (exact)
    const int edgeBlocks = (ETOT + 255) / 256;         // 3321
    const int aggBlocks  = (int)(((size_t)ETOT * 64 + 255) / 256);  // 212500
    const int elemBlocks = NNODES * F / 256;           // 12500 (exact)

    // ---------------- layer 1 ----------------
    hipMemsetAsync(z,   0, (size_t)NNODES * 4, stream);
    hipMemsetAsync(acc, 0, (size_t)NNODES * F * 4, stream);
    node_linear<<<nodeBlocks, 256, 0, stream>>>(x, W0, as0, ad0, h, as_, ad_);
    edge_softmax_den<<<edgeBlocks, 256, 0, stream>>>(src, dst, as_, ad_, ex, z);
    edge_aggregate<<<aggBlocks, 256, 0, stream>>>(src, dst, h, ex, z, acc);
    bias_act<<<elemBlocks, 256, 0, stream>>>(acc, b0);

    // ---------------- layer 2 ---------------- (input = acc)
    node_linear<<<nodeBlocks, 256, 0, stream>>>(acc, W1, as1, ad1, h, as_, ad_);
    hipMemsetAsync(z,   0, (size_t)NNODES * 4, stream);
    hipMemsetAsync(acc, 0, (size_t)NNODES * F * 4, stream);
    edge_softmax_den<<<edgeBlocks, 256, 0, stream>>>(src, dst, as_, ad_, ex, z);
    edge_aggregate<<<aggBlocks, 256, 0, stream>>>(src, dst, h, ex, z, acc);
    bias_act_res<<<elemBlocks, 256, 0, stream>>>(acc, b1, x, out);
}

// Round 2
// 347.777 us; speedup vs baseline: 1.8558x; 1.8558x over previous
//
#include <hip/hip_runtime.h>
#include <math.h>

#define NNODES 50000
#define NEDGES 800000
#define ETOT   (NEDGES + NNODES)   // edges + self loops
#define F      64
#define SCAN_BLOCKS ((NNODES + 255) / 256)   // 196

// ---------------------------------------------------------------------------
// Kernel A: h = x @ W ; alpha_s = h . a_src ; alpha_d = h . a_dst
// One wave (64 lanes) per node; block = 256 threads = 4 nodes.
// ---------------------------------------------------------------------------
__global__ __launch_bounds__(256) void node_linear(
    const float* __restrict__ x, const float* __restrict__ W,
    const float* __restrict__ a_src, const float* __restrict__ a_dst,
    float* __restrict__ h, float* __restrict__ as_, float* __restrict__ ad_)
{
    __shared__ float Ws[F * F];
    __shared__ float asv[F], adv[F];
    __shared__ float xrow[4][F];

    const int tid  = threadIdx.x;
    const int wave = tid >> 6;
    const int lane = tid & 63;
    const int node = blockIdx.x * 4 + wave;   // grid exact: NNODES % 4 == 0

    for (int i = tid; i < F * F; i += 256) Ws[i] = W[i];
    if (tid < F) { asv[tid] = a_src[tid]; adv[tid] = a_dst[tid]; }
    xrow[wave][lane] = x[node * F + lane];
    __syncthreads();

    float acc = 0.f;
#pragma unroll
    for (int k = 0; k < F; ++k)
        acc = fmaf(xrow[wave][k], Ws[k * F + lane], acc);

    h[node * F + lane] = acc;

    float vs = acc * asv[lane];
    float vd = acc * adv[lane];
#pragma unroll
    for (int off = 32; off > 0; off >>= 1) {
        vs += __shfl_down(vs, off, 64);
        vd += __shfl_down(vd, off, 64);
    }
    if (lane == 0) { as_[node] = vs; ad_[node] = vd; }
}

// ---------------------------------------------------------------------------
// CSR build: histogram -> 3-kernel exclusive scan -> scatter
// ---------------------------------------------------------------------------
__global__ __launch_bounds__(256) void hist_dst(
    const int* __restrict__ dst, int* __restrict__ cnt)
{
    const int e = blockIdx.x * 256 + threadIdx.x;
    if (e >= ETOT) return;
    const int d = (e < NEDGES) ? dst[e] : (e - NEDGES);
    atomicAdd(&cnt[d], 1);
}

__global__ __launch_bounds__(256) void scan1(
    const int* __restrict__ cnt, int* __restrict__ rowptr, int* __restrict__ bsum)
{
    __shared__ int s[256];
    const int i = blockIdx.x * 256 + threadIdx.x;
    const int v = (i < NNODES) ? cnt[i] : 0;
    s[threadIdx.x] = v;
    __syncthreads();
    for (int off = 1; off < 256; off <<= 1) {
        int t = (threadIdx.x >= off) ? s[threadIdx.x - off] : 0;
        __syncthreads();
        s[threadIdx.x] += t;
        __syncthreads();
    }
    if (i < NNODES) rowptr[i] = s[threadIdx.x] - v;       // exclusive
    if (threadIdx.x == 255) bsum[blockIdx.x] = s[255];    // block total
}

__global__ __launch_bounds__(256) void scan2(int* __restrict__ bsum)
{
    __shared__ int s[256];
    const int v = (threadIdx.x < SCAN_BLOCKS) ? bsum[threadIdx.x] : 0;
    s[threadIdx.x] = v;
    __syncthreads();
    for (int off = 1; off < 256; off <<= 1) {
        int t = (threadIdx.x >= off) ? s[threadIdx.x - off] : 0;
        __syncthreads();
        s[threadIdx.x] += t;
        __syncthreads();
    }
    if (threadIdx.x < SCAN_BLOCKS) bsum[threadIdx.x] = s[threadIdx.x] - v;  // exclusive base
}

__global__ __launch_bounds__(256) void scan3(
    int* __restrict__ rowptr, const int* __restrict__ bsum, int* __restrict__ cursor)
{
    const int i = blockIdx.x * 256 + threadIdx.x;
    if (i < NNODES) {
        const int r = rowptr[i] + bsum[blockIdx.x];
        rowptr[i] = r;
        cursor[i] = r;
    }
    if (i == 0) rowptr[NNODES] = ETOT;
}

__global__ __launch_bounds__(256) void scatter_edges(
    const int* __restrict__ src, const int* __restrict__ dst,
    int* __restrict__ cursor, int* __restrict__ csr_src)
{
    const int e = blockIdx.x * 256 + threadIdx.x;
    if (e >= ETOT) return;
    int s, d;
    if (e < NEDGES) { s = src[e]; d = dst[e]; }
    else            { s = e - NEDGES; d = s; }
    const int pos = atomicAdd(&cursor[d], 1);
    csr_src[pos] = s;
}

// ---------------------------------------------------------------------------
// Fused per-node softmax + aggregation + bias + LeakyReLU(0.01) [+ residual].
// One wave per node. Two edges in flight per iteration: lanes 0-31 take even
// edges, lanes 32-63 odd edges, each lane carrying a float2 feature pair.
// Halves are combined with __shfl_xor(...,32) at the end.
// ---------------------------------------------------------------------------
__global__ __launch_bounds__(256) void gat_aggregate(
    const int* __restrict__ rowptr, const int* __restrict__ csr_src,
    const float* __restrict__ h, const float* __restrict__ as_,
    const float* __restrict__ ad_, const float* __restrict__ bias,
    const float* __restrict__ resid, float* __restrict__ out, int addResidual)
{
    const int tid  = threadIdx.x;
    const int wave = tid >> 6;
    const int lane = tid & 63;
    const int node = blockIdx.x * 4 + wave;
    const int half = lane >> 5;   // which edge of the pair
    const int fl   = lane & 31;   // feature-pair index

    const float ad_n = ad_[node];
    const int beg = rowptr[node];
    const int end = rowptr[node + 1];

    float accx = 0.f, accy = 0.f, z = 0.f;
    for (int i = beg + half; i < end; i += 2) {
        const int s = csr_src[i];                      // broadcast within half-wave
        float t = as_[s] + ad_n;
        t = (t > 0.f) ? t : 0.2f * t;
        const float ev = __expf(t);
        const float2 hv = *(const float2*)(h + s * F + fl * 2);
        z += ev;
        accx = fmaf(ev, hv.x, accx);
        accy = fmaf(ev, hv.y, accy);
    }
    accx += __shfl_xor(accx, 32, 64);
    accy += __shfl_xor(accy, 32, 64);
    z    += __shfl_xor(z,    32, 64);

    const float inv = 1.f / (z + 1e-16f);
    float vx = accx * inv + bias[fl * 2];
    float vy = accy * inv + bias[fl * 2 + 1];
    vx = (vx > 0.f) ? vx : 0.01f * vx;
    vy = (vy > 0.f) ? vy : 0.01f * vy;
    if (addResidual) {
        const float2 r = *(const float2*)(resid + node * F + fl * 2);
        vx += r.x; vy += r.y;
    }
    if (half == 0) {
        float2 v; v.x = vx; v.y = vy;
        *(float2*)(out + node * F + fl * 2) = v;
    }
}

extern "C" void kernel_launch(void* const* d_in, const int* in_sizes, int n_in,
                              void* d_out, int out_size, void* d_ws, size_t ws_size,
                              hipStream_t stream)
{
    const float* x   = (const float*)d_in[0];
    const int*   ei  = (const int*)  d_in[1];   // [2, NEDGES] row-major
    const float* W0  = (const float*)d_in[2];
    const float* as0 = (const float*)d_in[3];
    const float* ad0 = (const float*)d_in[4];
    const float* b0  = (const float*)d_in[5];
    const float* W1  = (const float*)d_in[6];
    const float* as1 = (const float*)d_in[7];
    const float* ad1 = (const float*)d_in[8];
    const float* b1  = (const float*)d_in[9];
    float* out = (float*)d_out;

    const int* src = ei;
    const int* dst = ei + NEDGES;

    // workspace carve-up
    char* ws = (char*)d_ws;
    float* h      = (float*)ws; ws += (size_t)NNODES * F * 4;
    float* hmid   = (float*)ws; ws += (size_t)NNODES * F * 4;   // layer-1 output
    float* as_    = (float*)ws; ws += (size_t)NNODES * 4;
    float* ad_    = (float*)ws; ws += (size_t)NNODES * 4;
    int*   cnt    = (int*)ws;   ws += (size_t)NNODES * 4;
    int*   rowptr = (int*)ws;   ws += (size_t)(NNODES + 1) * 4;
    int*   cursor = (int*)ws;   ws += (size_t)NNODES * 4;
    int*   bsum   = (int*)ws;   ws += (size_t)SCAN_BLOCKS * 4;
    int*   csrsrc = (int*)ws;   ws += (size_t)ETOT * 4;

    const int nodeBlocks = NNODES / 4;             // 12500 (exact)
    const int edgeBlocks = (ETOT + 255) / 256;     // 3321

    // ---------------- CSR build (shared by both layers) ----------------
    hipMemsetAsync(cnt, 0, (size_t)NNODES * 4, stream);
    hist_dst<<<edgeBlocks, 256, 0, stream>>>(dst, cnt);
    scan1<<<SCAN_BLOCKS, 256, 0, stream>>>(cnt, rowptr, bsum);
    scan2<<<1, 256, 0, stream>>>(bsum);
    scan3<<<SCAN_BLOCKS, 256, 0, stream>>>(rowptr, bsum, cursor);
    scatter_edges<<<edgeBlocks, 256, 0, stream>>>(src, dst, cursor, csrsrc);

    // ---------------- layer 1 ----------------
    node_linear<<<nodeBlocks, 256, 0, stream>>>(x, W0, as0, ad0, h, as_, ad_);
    gat_aggregate<<<nodeBlocks, 256, 0, stream>>>(rowptr, csrsrc, h, as_, ad_,
                                                  b0, nullptr, hmid, 0);

    // ---------------- layer 2 ----------------
    node_linear<<<nodeBlocks, 256, 0, stream>>>(hmid, W1, as1, ad1, h, as_, ad_);
    gat_aggregate<<<nodeBlocks, 256, 0, stream>>>(rowptr, csrsrc, h, as_, ad_,
                                                  b1, x, out, 1);
}

// Round 3
// 275.322 us; speedup vs baseline: 2.3441x; 1.2632x over previous
//
#include <hip/hip_runtime.h>
#include <math.h>

#define NNODES 50000
#define NEDGES 800000
#define ETOT   (NEDGES + NNODES)   // edges + self loops
#define F      64
#define SCAN_BLOCKS ((NNODES + 255) / 256)   // 196
#define LIN_BLOCKS  (NNODES / 16)            // 3125 (16 nodes / block)
#define EDGE_BLOCKS ((ETOT + 255) / 256)     // 3321
#define AGG_BLOCKS  (NNODES / 4)             // 12500 (4 nodes / block)

// ---------------------------------------------------------------------------
// Linear body: h = x @ W ; as_ = h.a_src ; ad_ = h.a_dst
// Block = 256 threads = 4 waves = 16 nodes. Each lane computes 4 output cols
// (float4 of W via ds_read_b128); quarter-wave (16 lanes) per node.
// ---------------------------------------------------------------------------
__device__ __forceinline__ void linear_body(
    const float* __restrict__ x, const float* __restrict__ W,
    const float* __restrict__ a_src, const float* __restrict__ a_dst,
    float* __restrict__ h, float* __restrict__ as_, float* __restrict__ ad_,
    int blk)
{
    __shared__ float Ws[F * F];          // 16 KB
    __shared__ float xs[16][F + 1];      // +1 pad: 4 broadcast rows hit 4 banks
    __shared__ float asv[F], adv[F];

    const int tid = threadIdx.x;
    const int wv  = tid >> 6;
    const int ln  = tid & 63;
    const int q   = ln >> 4;             // node within wave
    const int fl4 = (ln & 15) * 4;       // output col quad
    const int nb  = wv * 4 + q;          // node within block (0..15)
    const int node = blk * 16 + nb;

    // stage W (4096 floats, 4 float4s per thread)
    for (int i = tid * 4; i < F * F; i += 256 * 4)
        *(float4*)&Ws[i] = *(const float4*)&W[i];
    if (tid < F) { asv[tid] = a_src[tid]; adv[tid] = a_dst[tid]; }
    {   // stage x rows (16 nodes x 64)
        const int n  = tid >> 4;
        const int c4 = (tid & 15) * 4;
        const float4 v = *(const float4*)&x[(blk * 16 + n) * F + c4];
        xs[n][c4] = v.x; xs[n][c4 + 1] = v.y; xs[n][c4 + 2] = v.z; xs[n][c4 + 3] = v.w;
    }
    __syncthreads();

    float4 acc = {0.f, 0.f, 0.f, 0.f};
#pragma unroll
    for (int k = 0; k < F; ++k) {
        const float xv = xs[nb][k];
        const float4 w = *(const float4*)&Ws[k * F + fl4];
        acc.x = fmaf(xv, w.x, acc.x);
        acc.y = fmaf(xv, w.y, acc.y);
        acc.z = fmaf(xv, w.z, acc.z);
        acc.w = fmaf(xv, w.w, acc.w);
    }

    *(float4*)&h[node * F + fl4] = acc;

    float vs = acc.x * asv[fl4] + acc.y * asv[fl4 + 1]
             + acc.z * asv[fl4 + 2] + acc.w * asv[fl4 + 3];
    float vd = acc.x * adv[fl4] + acc.y * adv[fl4 + 1]
             + acc.z * adv[fl4 + 2] + acc.w * adv[fl4 + 3];
#pragma unroll
    for (int off = 1; off < 16; off <<= 1) {
        vs += __shfl_xor(vs, off, 64);
        vd += __shfl_xor(vd, off, 64);
    }
    if ((ln & 15) == 0) { as_[node] = vs; ad_[node] = vd; }
}

// Fused: blocks [0, LIN_BLOCKS) do layer-1 linear; the rest do dst histogram.
__global__ __launch_bounds__(256) void linear1_hist(
    const float* __restrict__ x, const float* __restrict__ W,
    const float* __restrict__ a_src, const float* __restrict__ a_dst,
    float* __restrict__ h, float* __restrict__ as_, float* __restrict__ ad_,
    const int* __restrict__ dst, int* __restrict__ cnt)
{
    if (blockIdx.x >= LIN_BLOCKS) {
        const int e = (blockIdx.x - LIN_BLOCKS) * 256 + threadIdx.x;
        if (e < ETOT) {
            const int d = (e < NEDGES) ? dst[e] : (e - NEDGES);
            atomicAdd(&cnt[d], 1);
        }
        return;
    }
    linear_body(x, W, a_src, a_dst, h, as_, ad_, blockIdx.x);
}

__global__ __launch_bounds__(256) void node_linear(
    const float* __restrict__ x, const float* __restrict__ W,
    const float* __restrict__ a_src, const float* __restrict__ a_dst,
    float* __restrict__ h, float* __restrict__ as_, float* __restrict__ ad_)
{
    linear_body(x, W, a_src, a_dst, h, as_, ad_, blockIdx.x);
}

// ---------------------------------------------------------------------------
// CSR build: scan + scatter
// ---------------------------------------------------------------------------
__global__ __launch_bounds__(256) void scan1(
    const int* __restrict__ cnt, int* __restrict__ rowptr, int* __restrict__ bsum)
{
    __shared__ int s[256];
    const int i = blockIdx.x * 256 + threadIdx.x;
    const int v = (i < NNODES) ? cnt[i] : 0;
    s[threadIdx.x] = v;
    __syncthreads();
    for (int off = 1; off < 256; off <<= 1) {
        int t = (threadIdx.x >= off) ? s[threadIdx.x - off] : 0;
        __syncthreads();
        s[threadIdx.x] += t;
        __syncthreads();
    }
    if (i < NNODES) rowptr[i] = s[threadIdx.x] - v;
    if (threadIdx.x == 255) bsum[blockIdx.x] = s[255];
}

__global__ __launch_bounds__(256) void scan2(int* __restrict__ bsum)
{
    __shared__ int s[256];
    const int v = (threadIdx.x < SCAN_BLOCKS) ? bsum[threadIdx.x] : 0;
    s[threadIdx.x] = v;
    __syncthreads();
    for (int off = 1; off < 256; off <<= 1) {
        int t = (threadIdx.x >= off) ? s[threadIdx.x - off] : 0;
        __syncthreads();
        s[threadIdx.x] += t;
        __syncthreads();
    }
    if (threadIdx.x < SCAN_BLOCKS) bsum[threadIdx.x] = s[threadIdx.x] - v;
}

__global__ __launch_bounds__(256) void scan3(
    int* __restrict__ rowptr, const int* __restrict__ bsum, int* __restrict__ cursor)
{
    const int i = blockIdx.x * 256 + threadIdx.x;
    if (i < NNODES) {
        const int r = rowptr[i] + bsum[blockIdx.x];
        rowptr[i] = r;
        cursor[i] = r;
    }
    if (i == 0) rowptr[NNODES] = ETOT;
}

__global__ __launch_bounds__(256) void scatter_edges(
    const int* __restrict__ src, const int* __restrict__ dst,
    int* __restrict__ cursor, int* __restrict__ csr_src)
{
    const int e = blockIdx.x * 256 + threadIdx.x;
    if (e >= ETOT) return;
    int s, d;
    if (e < NEDGES) { s = src[e]; d = dst[e]; }
    else            { s = e - NEDGES; d = s; }
    const int pos = atomicAdd(&cursor[d], 1);
    csr_src[pos] = s;
}

// ---------------------------------------------------------------------------
// Fused softmax + aggregate + bias + LeakyReLU(0.01) [+ residual].
// One wave per node; 16 lanes per edge (float4/lane) -> 4 edges in flight.
// ---------------------------------------------------------------------------
__global__ __launch_bounds__(256) void gat_aggregate(
    const int* __restrict__ rowptr, const int* __restrict__ csr_src,
    const float* __restrict__ h, const float* __restrict__ as_,
    const float* __restrict__ ad_, const float* __restrict__ bias,
    const float* __restrict__ resid, float* __restrict__ out, int addResidual)
{
    const int tid  = threadIdx.x;
    const int wv   = tid >> 6;
    const int ln   = tid & 63;
    const int node = blockIdx.x * 4 + wv;
    const int g    = ln >> 4;          // edge slot within quad
    const int fl4  = (ln & 15) * 4;    // feature quad

    const float ad_n = ad_[node];
    const int beg = rowptr[node];
    const int end = rowptr[node + 1];

    float4 acc = {0.f, 0.f, 0.f, 0.f};
    float z = 0.f;
    for (int i = beg + g; i < end; i += 4) {
        const int s = csr_src[i];
        float t = as_[s] + ad_n;
        t = (t > 0.f) ? t : 0.2f * t;
        const float ev = __expf(t);
        const float4 hv = *(const float4*)(h + s * F + fl4);
        z += ev;
        acc.x = fmaf(ev, hv.x, acc.x);
        acc.y = fmaf(ev, hv.y, acc.y);
        acc.z = fmaf(ev, hv.z, acc.z);
        acc.w = fmaf(ev, hv.w, acc.w);
    }
#pragma unroll
    for (int off = 16; off < 64; off <<= 1) {
        acc.x += __shfl_xor(acc.x, off, 64);
        acc.y += __shfl_xor(acc.y, off, 64);
        acc.z += __shfl_xor(acc.z, off, 64);
        acc.w += __shfl_xor(acc.w, off, 64);
        z     += __shfl_xor(z,     off, 64);
    }

    if (g == 0) {
        const float inv = 1.f / (z + 1e-16f);
        const float4 b = *(const float4*)&bias[fl4];
        float4 v;
        v.x = acc.x * inv + b.x; v.y = acc.y * inv + b.y;
        v.z = acc.z * inv + b.z; v.w = acc.w * inv + b.w;
        v.x = (v.x > 0.f) ? v.x : 0.01f * v.x;
        v.y = (v.y > 0.f) ? v.y : 0.01f * v.y;
        v.z = (v.z > 0.f) ? v.z : 0.01f * v.z;
        v.w = (v.w > 0.f) ? v.w : 0.01f * v.w;
        if (addResidual) {
            const float4 r = *(const float4*)(resid + node * F + fl4);
            v.x += r.x; v.y += r.y; v.z += r.z; v.w += r.w;
        }
        *(float4*)(out + node * F + fl4) = v;
    }
}

extern "C" void kernel_launch(void* const* d_in, const int* in_sizes, int n_in,
                              void* d_out, int out_size, void* d_ws, size_t ws_size,
                              hipStream_t stream)
{
    const float* x   = (const float*)d_in[0];
    const int*   ei  = (const int*)  d_in[1];   // [2, NEDGES] row-major
    const float* W0  = (const float*)d_in[2];
    const float* as0 = (const float*)d_in[3];
    const float* ad0 = (const float*)d_in[4];
    const float* b0  = (const float*)d_in[5];
    const float* W1  = (const float*)d_in[6];
    const float* as1 = (const float*)d_in[7];
    const float* ad1 = (const float*)d_in[8];
    const float* b1  = (const float*)d_in[9];
    float* out = (float*)d_out;

    const int* src = ei;
    const int* dst = ei + NEDGES;

    // workspace carve-up
    char* ws = (char*)d_ws;
    float* h      = (float*)ws; ws += (size_t)NNODES * F * 4;
    float* hmid   = (float*)ws; ws += (size_t)NNODES * F * 4;
    float* as_    = (float*)ws; ws += (size_t)NNODES * 4;
    float* ad_    = (float*)ws; ws += (size_t)NNODES * 4;
    int*   cnt    = (int*)ws;   ws += (size_t)NNODES * 4;
    int*   rowptr = (int*)ws;   ws += (size_t)(NNODES + 1) * 4;
    int*   cursor = (int*)ws;   ws += (size_t)NNODES * 4;
    int*   bsum   = (int*)ws;   ws += (size_t)SCAN_BLOCKS * 4;
    int*   csrsrc = (int*)ws;   ws += (size_t)ETOT * 4;

    // ---------------- CSR build + layer-1 linear (fused) ----------------
    hipMemsetAsync(cnt, 0, (size_t)NNODES * 4, stream);
    linear1_hist<<<LIN_BLOCKS + EDGE_BLOCKS, 256, 0, stream>>>(
        x, W0, as0, ad0, h, as_, ad_, dst, cnt);
    scan1<<<SCAN_BLOCKS, 256, 0, stream>>>(cnt, rowptr, bsum);
    scan2<<<1, 256, 0, stream>>>(bsum);
    scan3<<<SCAN_BLOCKS, 256, 0, stream>>>(rowptr, bsum, cursor);
    scatter_edges<<<EDGE_BLOCKS, 256, 0, stream>>>(src, dst, cursor, csrsrc);

    // ---------------- layer 1 aggregate ----------------
    gat_aggregate<<<AGG_BLOCKS, 256, 0, stream>>>(rowptr, csrsrc, h, as_, ad_,
                                                  b0, nullptr, hmid, 0);

    // ---------------- layer 2 ----------------
    node_linear<<<LIN_BLOCKS, 256, 0, stream>>>(hmid, W1, as1, ad1, h, as_, ad_);
    gat_aggregate<<<AGG_BLOCKS, 256, 0, stream>>>(rowptr, csrsrc, h, as_, ad_,
                                                  b1, x, out, 1);
}